// Round 4
// baseline (213.957 us; speedup 1.0000x reference)
//
#include <hip/hip_runtime.h>
#include <math.h>

#define NQ 12
#define DIM 4096

// ---- GF(2)-linear index maps ----------------------------------------------
// LDS swizzle for the 64x64 exchange patterns (bijective, GF(2)-linear)
__host__ __device__ constexpr int physc(int i){ return i ^ ((i>>6)&63); }
// CNOT ring CNOT(0,1)..CNOT(10,11),CNOT(11,0); wire w <-> bit (11-w).
// F: amplitude at i lands at F(i).  G = F^{-1}.  (verified rounds 1-3)
__host__ __device__ constexpr int Fmap(int y){
  int s = y ^ (y>>1); s ^= s>>2; s ^= s>>4; s ^= s>>8;
  return (s ^ ((s&1)<<11)) & 0xFFF;
}
__host__ __device__ constexpr int Gmap(int y){ return ((y ^ (y>>1)) ^ ((y&1)*0xC00)) & 0xFFF; }

__device__ __forceinline__ float sgnf(float M, int bitv){
  return __int_as_float(__float_as_int(M) ^ (bitv<<31));
}

// Fused 2x2 complex gate on owned bit J of 64 register-resident amplitudes.
template<int J>
__device__ __forceinline__ void gate_on_bit64(float2 (&s)[64], const float* __restrict__ u){
  const float u00x=u[0], u00y=u[1], u01x=u[2], u01y=u[3];
  const float u10x=u[4], u10y=u[5], u11x=u[6], u11y=u[7];
#pragma unroll
  for (int k = 0; k < 64; ++k){
    if (k & (1 << J)) continue;
    const int k1 = k | (1 << J);
    const float ax = s[k].x, ay = s[k].y, bx = s[k1].x, by = s[k1].y;
    s[k].x  = fmaf(u00x, ax, fmaf(-u00y, ay, fmaf(u01x, bx, -u01y*by)));
    s[k].y  = fmaf(u00x, ay, fmaf( u00y, ax, fmaf(u01x, by,  u01y*bx)));
    s[k1].x = fmaf(u10x, ax, fmaf(-u10y, ay, fmaf(u11x, bx, -u11y*by)));
    s[k1].y = fmaf(u10x, ay, fmaf( u10y, ax, fmaf(u11x, by,  u11y*bx)));
  }
}

// One ownership half: 6 gates on reg bits 5..0. U layout is phase-major so
// both halves and both layers share this ONE code body (p-loop, no unroll).
__device__ __forceinline__ void gate6(float2 (&s)[64], const float* __restrict__ Up){
  gate_on_bit64<5>(s, Up + 0*8);
  gate_on_bit64<4>(s, Up + 1*8);
  gate_on_bit64<3>(s, Up + 2*8);
  gate_on_bit64<2>(s, Up + 3*8);
  gate_on_bit64<1>(s, Up + 4*8);
  gate_on_bit64<0>(s, Up + 5*8);
}

// Precompute 24 fused U = Rz*Ry*Rx in PHASE order:
// U[p*6+g] = fused(layer = p>>1, wire = (p&1)*6 + g), applied to reg bit 5-g.
__global__ __launch_bounds__(64)
void prep_gates(const float* __restrict__ w, float* __restrict__ U){
  const int t = threadIdx.x;
  if (t >= 24) return;
  const int p = t / 6, g = t % 6;
  const int layer = p >> 1;
  const int q = (p & 1) * 6 + g;
  const float ax = 0.5f * w[layer*36 + q*3 + 0];
  const float ay = 0.5f * w[layer*36 + q*3 + 1];
  const float az = 0.5f * w[layer*36 + q*3 + 2];
  const float ca = cosf(ax), sa = sinf(ax);
  const float cb = cosf(ay), sb = sinf(ay);
  const float cc = cosf(az), sc = sinf(az);
  const float m00x =  cb*ca, m00y =  sb*sa;
  const float m01x = -sb*ca, m01y = -cb*sa;
  const float m10x =  sb*ca, m10y = -cb*sa;
  const float m11x =  cb*ca, m11y = -sb*sa;
  float* o = U + t*8;
  o[0] = cc*m00x + sc*m00y;  o[1] = cc*m00y - sc*m00x;
  o[2] = cc*m01x + sc*m01y;  o[3] = cc*m01y - sc*m01x;
  o[4] = cc*m10x - sc*m10y;  o[5] = cc*m10y + sc*m10x;
  o[6] = cc*m11x - sc*m11y;  o[7] = cc*m11y + sc*m11x;
}

// Single-wave kernel: 64 threads, 64 amps/thread. No cross-wave barriers.
__global__ __launch_bounds__(64, 2)
void qsim_kernel(const float* __restrict__ x, const float* __restrict__ U,
                 float* __restrict__ out){
  __shared__ float2 st[DIM];          // 32 KB -> 5 blocks/CU
  const int lane = threadIdx.x;
  const int b    = blockIdx.x;

  // ---- encoding angles: lanes 0-11 sincos, broadcast via shfl -------------
  float c0 = 0.f, s0 = 0.f;
  if (lane < NQ){
    const float a = x[b*NQ + lane] * 1.5707963267948966f;
    sincosf(a, &s0, &c0);
  }
  float cw[NQ], sw[NQ];
#pragma unroll
  for (int w = 0; w < NQ; ++w){
    cw[w] = __shfl(c0, w);
    sw[w] = __shfl(s0, w);
  }

  // ---- init product state, ownership A: i = lane | (k<<6) -----------------
  // lane bit p <-> state bit p <-> wire 11-p;  k bit j <-> state bit 6+j <-> wire 5-j
  float2 s[64];
  {
    float base = 1.f;
#pragma unroll
    for (int p = 0; p < 6; ++p) base *= ((lane>>p)&1) ? sw[11-p] : cw[11-p];
    float t01[4], t23[4], bt45[4];
#pragma unroll
    for (int m = 0; m < 4; ++m){
      t01[m]  = ((m&1)?sw[5]:cw[5]) * ((m&2)?sw[4]:cw[4]);
      t23[m]  = ((m&1)?sw[3]:cw[3]) * ((m&2)?sw[2]:cw[2]);
      bt45[m] = base * (((m&1)?sw[1]:cw[1]) * ((m&2)?sw[0]:cw[0]));
    }
    float t0123[16];
#pragma unroll
    for (int m = 0; m < 16; ++m) t0123[m] = t01[m&3] * t23[m>>2];
#pragma unroll
    for (int k = 0; k < 64; ++k)
      s[k] = make_float2(bt45[k>>4] * t0123[k&15], 0.f);
  }

  // ---- exchange address bases (all GF(2)-linear) --------------------------
  const int bB  = 65*lane;                                   // B: (65*lane)^k
  const int g6  = lane ^ (lane>>1);
  const int bGA = g6 ^ ((lane&1) ? 0xC30 : 0);               // phys(G(lane))

  // ---- 4 phases: (L0,A),(L0,B),(L1,A),(L1,B); ONE gate6 code copy ---------
#pragma clang loop unroll(disable)
  for (int p = 0; p < 4; ++p){
    gate6(s, U + p*48);
    if (p == 3) break;
    __syncthreads();                  // 1-wave block: just a waitcnt drain
    if ((p & 1) == 0){
#pragma unroll
      for (int k = 0; k < 64; ++k) st[lane ^ (65*k)] = s[k];   // write A
    } else {
#pragma unroll
      for (int k = 0; k < 64; ++k) st[bB ^ k] = s[k];          // write B
    }
    __syncthreads();
    if ((p & 1) == 0){
#pragma unroll
      for (int k = 0; k < 64; ++k) s[k] = st[bB ^ k];          // read B
    } else {
#pragma unroll
      for (int k = 0; k < 64; ++k)                              // gather A
        s[k] = st[bGA ^ physc(Gmap(k << 6))];                   // (ring folded)
    }
  }

  // ---- output: layer-1 ring as index map; suffix-parity Walsh over k ------
  // i = k | (lane<<6); sign for wire w = bit(11-w) of F(k) ^ F(lane<<6).
  const int ft = Fmap(lane << 6);
  float e5[32], d5[32];
#pragma unroll
  for (int k = 0; k < 32; ++k){
    const float pa = fmaf(s[k].x,    s[k].x,    s[k].y   *s[k].y);
    const float pb = fmaf(s[k+32].x, s[k+32].x, s[k+32].y*s[k+32].y);
    e5[k] = pa + pb; d5[k] = pa - pb;
  }
  float t16a[16];
#pragma unroll
  for (int k = 0; k < 16; ++k) t16a[k] = e5[k] + e5[k+16];
  float t8a[8];
#pragma unroll
  for (int k = 0; k < 8; ++k) t8a[k] = t16a[k] + t16a[k+8];
  float t4a[4];
#pragma unroll
  for (int k = 0; k < 4; ++k) t4a[k] = t8a[k] + t8a[k+4];
  const float T = (t4a[0]+t4a[1]) + (t4a[2]+t4a[3]);

  float s1[16], d1[16];
#pragma unroll
  for (int k = 0; k < 16; ++k){ s1[k] = d5[k] + d5[k+16]; d1[k] = d5[k] - d5[k+16]; }
  float u8a[8];
#pragma unroll
  for (int k = 0; k < 8; ++k) u8a[k] = s1[k] + s1[k+8];
  float u4a[4];
#pragma unroll
  for (int k = 0; k < 4; ++k) u4a[k] = u8a[k] + u8a[k+4];
  const float P5 = (u4a[0]+u4a[1]) + (u4a[2]+u4a[3]);

  float s2[8], d2[8];
#pragma unroll
  for (int k = 0; k < 8; ++k){ s2[k] = d1[k] + d1[k+8]; d2[k] = d1[k] - d1[k+8]; }
  const float P45 = ((s2[0]+s2[1])+(s2[2]+s2[3])) + ((s2[4]+s2[5])+(s2[6]+s2[7]));

  float s3[4], d3[4];
#pragma unroll
  for (int k = 0; k < 4; ++k){ s3[k] = d2[k] + d2[k+4]; d3[k] = d2[k] - d2[k+4]; }
  const float P345 = (s3[0]+s3[1]) + (s3[2]+s3[3]);

  const float s4a = d3[0] + d3[2], s4b = d3[1] + d3[3];
  const float d4a = d3[0] - d3[2], d4b = d3[1] - d3[3];
  const float P2345   = s4a + s4b;
  const float P12345  = d4a + d4b;
  const float P012345 = d4a - d4b;

  float r[NQ];
  r[0]  = sgnf(P012345, (ft >> 11) & 1);
#pragma unroll
  for (int w = 1; w <= 5; ++w)
    r[w] = sgnf(T, (ft >> (11 - w)) & 1);
  r[6]  = sgnf(P5,      (ft >> 5) & 1);
  r[7]  = sgnf(P45,     (ft >> 4) & 1);
  r[8]  = sgnf(P345,    (ft >> 3) & 1);
  r[9]  = sgnf(P2345,   (ft >> 2) & 1);
  r[10] = sgnf(P12345,  (ft >> 1) & 1);
  r[11] = sgnf(P012345,  ft       & 1);

  // ---- in-wave reduction, lane 0 stores 12 floats as 3x float4 ------------
#pragma unroll
  for (int off = 32; off; off >>= 1)
#pragma unroll
    for (int w = 0; w < NQ; ++w) r[w] += __shfl_down(r[w], off);
  if (lane == 0){
    float4* o = (float4*)(out + b*NQ);
    o[0] = make_float4(r[0], r[1], r[2],  r[3]);
    o[1] = make_float4(r[4], r[5], r[6],  r[7]);
    o[2] = make_float4(r[8], r[9], r[10], r[11]);
  }
}

extern "C" void kernel_launch(void* const* d_in, const int* in_sizes, int n_in,
                              void* d_out, int out_size, void* d_ws, size_t ws_size,
                              hipStream_t stream){
  const float* x = (const float*)d_in[0];
  const float* w = (const float*)d_in[1];
  float* out = (float*)d_out;
  float* U   = (float*)d_ws;          // 24 gates * 8 floats = 768 B
  const int B = in_sizes[0] / NQ;     // 2048

  prep_gates<<<1, 64, 0, stream>>>(w, U);
  qsim_kernel<<<B, 64, 0, stream>>>(x, U, out);
}

// Round 7
// 78.170 us; speedup vs baseline: 2.7371x; 2.7371x over previous
//
#include <hip/hip_runtime.h>
#include <math.h>

#define NQ 12
#define DIM 4096

// CNOT ring CNOT(0,1)..CNOT(10,11),CNOT(11,0); wire w <-> bit (11-w).
// F: amplitude at i lands at F(i) (verified r1-r3).  Bits of G = F^{-1}:
//   g_p = i_p ^ i_{p+1} (p=0..9), g_10 = i_10^i_11^i_0, g_11 = i_11^i_0.
__host__ __device__ constexpr int Fmap(int y){
  int s = y ^ (y>>1); s ^= s>>2; s ^= s>>4; s ^= s>>8;
  return (s ^ ((s&1)<<11)) & 0xFFF;
}

__device__ __forceinline__ float sgnf(float M, int bitv){
  return __int_as_float(__float_as_int(M) ^ (bitv<<31));
}

// Fused 2x2 complex gate on owned bit J (round-3 verified, explicit FMA).
template<int J>
__device__ __forceinline__ void gate_on_bit(float2 (&s)[16], const float* __restrict__ u){
  const float u00x=u[0], u00y=u[1], u01x=u[2], u01y=u[3];
  const float u10x=u[4], u10y=u[5], u11x=u[6], u11y=u[7];
#pragma unroll
  for (int k = 0; k < 16; ++k){
    if (k & (1 << J)) continue;
    const int k1 = k | (1 << J);
    const float ax = s[k].x, ay = s[k].y, bx = s[k1].x, by = s[k1].y;
    s[k].x  = fmaf(u00x, ax, fmaf(-u00y, ay, fmaf(u01x, bx, -u01y*by)));
    s[k].y  = fmaf(u00x, ay, fmaf( u00y, ax, fmaf(u01x, by,  u01y*bx)));
    s[k1].x = fmaf(u10x, ax, fmaf(-u10y, ay, fmaf(u11x, bx, -u11y*by)));
    s[k1].y = fmaf(u10x, ay, fmaf( u10y, ax, fmaf(u11x, by,  u11y*bx)));
  }
}

// Precompute 24 fused U = Rz*Ry*Rx (layer-major, qubit-minor; round-3 verified).
__global__ __launch_bounds__(64)
void prep_gates(const float* __restrict__ w, float* __restrict__ U){
  const int t = threadIdx.x;
  if (t >= 24) return;
  const int l = t / 12, q = t % 12;
  const float ax = 0.5f * w[l*36 + q*3 + 0];
  const float ay = 0.5f * w[l*36 + q*3 + 1];
  const float az = 0.5f * w[l*36 + q*3 + 2];
  const float ca = cosf(ax), sa = sinf(ax);
  const float cb = cosf(ay), sb = sinf(ay);
  const float cc = cosf(az), sc = sinf(az);
  const float m00x =  cb*ca, m00y =  sb*sa;
  const float m01x = -sb*ca, m01y = -cb*sa;
  const float m10x =  sb*ca, m10y = -cb*sa;
  const float m11x =  cb*ca, m11y = -sb*sa;
  float* o = U + t*8;
  o[0] = cc*m00x + sc*m00y;  o[1] = cc*m00y - sc*m00x;
  o[2] = cc*m01x + sc*m01y;  o[3] = cc*m01y - sc*m01x;
  o[4] = cc*m10x - sc*m10y;  o[5] = cc*m10y + sc*m10x;
  o[6] = cc*m11x - sc*m11y;  o[7] = cc*m11y + sc*m11x;
}

__global__ __launch_bounds__(256)
void qsim_kernel(const float* __restrict__ x, const float* __restrict__ U,
                 float* __restrict__ out){
  __shared__ float2 st[DIM];          // 32 KB
  float* red = (float*)st;
  char*  stb = (char*)st;
  const int tid  = threadIdx.x;
  const int lane = tid & 63;
  const int b    = blockIdx.x;

  // ---- encoding angles: lanes 0-11 of each wave sincos, shfl broadcast ----
  float c0 = 0.f, s0 = 0.f;
  if (lane < NQ){
    const float a = x[b*NQ + lane] * 1.5707963267948966f;
    sincosf(a, &s0, &c0);
  }
  float cw[NQ], sw[NQ];
#pragma unroll
  for (int w = 0; w < NQ; ++w){ cw[w] = __shfl(c0, w); sw[w] = __shfl(s0, w); }

  // ---- layer-0 single-qubit gates on the PRODUCT state: per-qubit 2-vecs --
  // Q[p] = U(l0, wire 11-p) * (c,s): {q0.x, q0.y, q1.x, q1.y}
  float4 Q[NQ];
#pragma unroll
  for (int p = 0; p < NQ; ++p){
    const int w = 11 - p;
    const float* u = U + w*8;
    Q[p].x = fmaf(u[0], cw[w], u[2]*sw[w]);
    Q[p].y = fmaf(u[1], cw[w], u[3]*sw[w]);
    Q[p].z = fmaf(u[4], cw[w], u[6]*sw[w]);
    Q[p].w = fmaf(u[5], cw[w], u[7]*sw[w]);
  }

  // ---- build post-ring state directly: s1[i] = prod_p Q[p][g_p(i)] --------
  // ownership A: i = tid | (k<<8); k bit j = state bit 8+j.
  const int gt = tid ^ (tid >> 1);          // bit p: tid_p ^ tid_{p+1}
  float bx, by;
  { const int e = gt & 1;
    bx = e ? Q[0].z : Q[0].x;  by = e ? Q[0].w : Q[0].y; }
#pragma unroll
  for (int p = 1; p <= 6; ++p){
    const int e = (gt >> p) & 1;
    const float fx = e ? Q[p].z : Q[p].x, fy = e ? Q[p].w : Q[p].y;
    const float nx = fmaf(bx, fx, -by*fy);
    by = fmaf(bx, fy, by*fx);  bx = nx;
  }
  const int t7 = (tid >> 7) & 1, t0 = tid & 1;
  float bax[2], bay[2];                      // base * Q7[t7^k0]
#pragma unroll
  for (int k0 = 0; k0 < 2; ++k0){
    const int e = t7 ^ k0;
    const float fx = e ? Q[7].z : Q[7].x, fy = e ? Q[7].w : Q[7].y;
    bax[k0] = fmaf(bx, fx, -by*fy);
    bay[k0] = fmaf(bx, fy,  by*fx);
  }
  float ax2[2][2], ay2[2][2];                // * Q8[k0^k1]
#pragma unroll
  for (int k1 = 0; k1 < 2; ++k1)
#pragma unroll
  for (int k0 = 0; k0 < 2; ++k0){
    const int e = k0 ^ k1;
    const float fx = e ? Q[8].z : Q[8].x, fy = e ? Q[8].w : Q[8].y;
    ax2[k1][k0] = fmaf(bax[k0], fx, -bay[k0]*fy);
    ay2[k1][k0] = fmaf(bax[k0], fy,  bay[k0]*fx);
  }
  float dx[2][2][2], dy[2][2][2];            // * Q9[k1^k2]
#pragma unroll
  for (int k2 = 0; k2 < 2; ++k2)
#pragma unroll
  for (int k1 = 0; k1 < 2; ++k1)
#pragma unroll
  for (int k0 = 0; k0 < 2; ++k0){
    const int e = k1 ^ k2;
    const float fx = e ? Q[9].z : Q[9].x, fy = e ? Q[9].w : Q[9].y;
    dx[k2][k1][k0] = fmaf(ax2[k1][k0], fx, -ay2[k1][k0]*fy);
    dy[k2][k1][k0] = fmaf(ax2[k1][k0], fy,  ay2[k1][k0]*fx);
  }
  float b2x[2][2], b2y[2][2];                // Q10[k2^k3^t0] * Q11[k3^t0]
#pragma unroll
  for (int k3 = 0; k3 < 2; ++k3)
#pragma unroll
  for (int k2 = 0; k2 < 2; ++k2){
    const int e10 = k2 ^ k3 ^ t0, e11 = k3 ^ t0;
    const float gx = e10 ? Q[10].z : Q[10].x, gy = e10 ? Q[10].w : Q[10].y;
    const float hx = e11 ? Q[11].z : Q[11].x, hy = e11 ? Q[11].w : Q[11].y;
    b2x[k3][k2] = fmaf(gx, hx, -gy*hy);
    b2y[k3][k2] = fmaf(gx, hy,  gy*hx);
  }
  float2 s[16];
#pragma unroll
  for (int k = 0; k < 16; ++k){
    const int k0 = k&1, k1 = (k>>1)&1, k2 = (k>>2)&1, k3 = (k>>3)&1;
    s[k].x = fmaf(dx[k2][k1][k0], b2x[k3][k2], -dy[k2][k1][k0]*b2y[k3][k2]);
    s[k].y = fmaf(dx[k2][k1][k0], b2y[k3][k2],  dy[k2][k1][k0]*b2x[k3][k2]);
  }

  // ---- per-pass BYTE bases (round-3 verified) -----------------------------
  const int m4 = (tid >> 4) & 1;
  const int bA = (tid ^ ((tid >> 4) & 15)) << 3;
  const int bB = ((tid & 15) | (m4 << 4) | ((tid >> 4) << 8)) << 3;
  const int bC = (((tid & 15) | (tid << 4)) ^ (m4 << 4)) << 3;

#define WRITE_A  _Pragma("unroll") for (int k = 0; k < 16; ++k) \
    *(float2*)(stb + ((bA ^ ((k & 1) << 7)) | (k << 11))) = s[k];
#define READ_B   _Pragma("unroll") for (int k = 0; k < 16; ++k) \
    s[k] = *(const float2*)(stb + (bB ^ (136 * k)));
#define WRITE_B  _Pragma("unroll") for (int k = 0; k < 16; ++k) \
    *(float2*)(stb + (bB ^ (136 * k))) = s[k];
#define READ_C   _Pragma("unroll") for (int k = 0; k < 16; ++k) \
    s[k] = *(const float2*)(stb + (bC ^ (k << 3)));

  // ================= layer 1 (the only state-vector gate passes) ===========
  gate_on_bit<0>(s, U + (12 + 3)*8);   // ownership A: reg bit j <-> wire 3-j
  gate_on_bit<1>(s, U + (12 + 2)*8);
  gate_on_bit<2>(s, U + (12 + 1)*8);
  gate_on_bit<3>(s, U + (12 + 0)*8);
  WRITE_A;
  __syncthreads();
  READ_B;                              // ownership B: reg bit j <-> wire 7-j
  gate_on_bit<0>(s, U + (12 + 7)*8);
  gate_on_bit<1>(s, U + (12 + 6)*8);
  gate_on_bit<2>(s, U + (12 + 5)*8);
  gate_on_bit<3>(s, U + (12 + 4)*8);
  WRITE_B;                             // same slots just read: no barrier
  __syncthreads();
  READ_C;                              // ownership C: reg bit j <-> wire 11-j
  gate_on_bit<0>(s, U + (12 + 11)*8);
  gate_on_bit<1>(s, U + (12 + 10)*8);
  gate_on_bit<2>(s, U + (12 +  9)*8);
  gate_on_bit<3>(s, U + (12 +  8)*8);

  // ---- output: layer-1 ring as index map; Walsh over k (round-3 verified) -
  const int ft = Fmap(tid << 4);
  float p2[16];
#pragma unroll
  for (int k = 0; k < 16; ++k) p2[k] = fmaf(s[k].x, s[k].x, s[k].y*s[k].y);
  float u8[8], v8[8];
#pragma unroll
  for (int l = 0; l < 8; ++l){ u8[l] = p2[l] + p2[l+8]; v8[l] = p2[l] - p2[l+8]; }
  const float T  = ((u8[0]+u8[1])+(u8[2]+u8[3])) + ((u8[4]+u8[5])+(u8[6]+u8[7]));
  const float S3 = ((v8[0]+v8[1])+(v8[2]+v8[3])) + ((v8[4]+v8[5])+(v8[6]+v8[7]));
  float a4[4];
#pragma unroll
  for (int l = 0; l < 4; ++l) a4[l] = v8[l] - v8[l+4];
  const float S23   = (a4[0]+a4[1]) + (a4[2]+a4[3]);
  const float b0 = a4[0]-a4[2], b1 = a4[1]-a4[3];
  const float S123  = b0 + b1;
  const float S0123 = b0 - b1;

  float r[NQ];
  r[0]  = sgnf(S0123, (ft >> 11) & 1);
#pragma unroll
  for (int w = 1; w <= 7; ++w)
    r[w] = sgnf(T, (ft >> (11 - w)) & 1);
  r[8]  = sgnf(S3,    (ft >> 3) & 1);
  r[9]  = sgnf(S23,   (ft >> 2) & 1);
  r[10] = sgnf(S123,  (ft >> 1) & 1);
  r[11] = sgnf(S0123,  ft       & 1);

  // ---- block reduction (round-3 verified) ---------------------------------
#pragma unroll
  for (int off = 32; off; off >>= 1)
#pragma unroll
    for (int w = 0; w < NQ; ++w) r[w] += __shfl_down(r[w], off);
  __syncthreads();
  const int wid = tid >> 6;
  if (lane == 0){
#pragma unroll
    for (int w = 0; w < NQ; ++w) red[wid*NQ + w] = r[w];
  }
  __syncthreads();
  if (tid < NQ)
    out[b*NQ + tid] = red[tid] + red[NQ + tid] + red[2*NQ + tid] + red[3*NQ + tid];
}

extern "C" void kernel_launch(void* const* d_in, const int* in_sizes, int n_in,
                              void* d_out, int out_size, void* d_ws, size_t ws_size,
                              hipStream_t stream){
  const float* x = (const float*)d_in[0];
  const float* w = (const float*)d_in[1];
  float* out = (float*)d_out;
  float* U   = (float*)d_ws;          // 24 gates * 8 floats = 768 B
  const int B = in_sizes[0] / NQ;     // 2048

  prep_gates<<<1, 64, 0, stream>>>(w, U);
  qsim_kernel<<<B, 256, 0, stream>>>(x, U, out);
}